// Round 2
// baseline (539.760 us; speedup 1.0000x reference)
//
#include <hip/hip_runtime.h>
#include <math.h>

#define V55  55
#define NT   128
#define EPSF 1e-5f
#define ATOFF (16*64*4)   // floats per A-tile buffer: [q=16][v=64] float4

// ---- staging: issue global loads (early) ----
#define STAGE_LOAD(TS, XV, ACT)                                                   \
    if (ACT) {                                                                    \
        _Pragma("unroll")                                                         \
        for (int j = 0; j < 8; ++j) {                                             \
            int c = (j << 3) + c8;                                                \
            XV[j] = x[xbase + (c * NT + (TS)) * V55 + vb];                        \
        }                                                                         \
    }

// ---- staging: mask-multiply + LDS write (late, after compute) ----
#define STAGE_WRITE(PAR, XV, ACT)                                                 \
    if (ACT) {                                                                    \
        int v = v0;                                                               \
        _Pragma("unroll")                                                         \
        for (int j = 0; j < 8; ++j) {                                             \
            int c = (j << 3) + c8;                                                \
            AT[(PAR) * ATOFF + ((c >> 2) * 64 + v) * 4 + (c & 3)] = XV[j] * msr[j]; \
            v -= 8; if (v < 0) v += V55;                                          \
        }                                                                         \
    }

// ---- GEMM: lane=v row from LDS (per-lane b128), W rows via scalar loads ----
#define COMPUTE(PAR, G, ACT)                                                      \
    {                                                                             \
        _Pragma("unroll") for (int k = 0; k < 8; ++k) G[k] = 0.f;                 \
        if (ACT) {                                                                \
            const float4* Ar = (const float4*)(AT + (PAR) * ATOFF) + lane;        \
            _Pragma("unroll")                                                     \
            for (int q = 0; q < 16; ++q) {                                        \
                float4 a = Ar[q * 64];                                            \
                _Pragma("unroll")                                                 \
                for (int cc = 0; cc < 4; ++cc) {                                  \
                    float av = (cc == 0) ? a.x : (cc == 1) ? a.y : (cc == 2) ? a.z : a.w; \
                    const float* Wp = Wm + (((q << 2) + cc) << 6) + d0;           \
                    _Pragma("unroll")                                             \
                    for (int k = 0; k < 8; ++k) G[k] = fmaf(av, Wp[k], G[k]);     \
                }                                                                 \
            }                                                                     \
            _Pragma("unroll")                                                     \
            for (int k = 0; k < 8; ++k)                                           \
                G[k] = fmaxf(fmaf(s1[k], G[k], sh1[k]), 0.f);                     \
        }                                                                         \
    }

// ---- emit: temporal shift (static gen pick, P = d0%3 literal) + bpermute
//      inverse-spatial-shift + BN2 + residual + relu, coalesced stores ----
#define EMITP(P, Gc, Gm1, Gm2, TOUT)                                              \
    {                                                                             \
        _Pragma("unroll")                                                         \
        for (int k = 0; k < 8; ++k) {                                             \
            const int off = (((P) + k) % 3) - 1;                                  \
            int dk = d0 + k;                                                      \
            int tsrc = (TOUT) + off;                                              \
            int vs = lane - dk;                                                   \
            if (vs < 0) vs += V55; if (vs < 0) vs += V55;                         \
            if (vs >= V55) vs -= V55;                                             \
            float gsel = (off == -1) ? Gm2[k] : (off == 0) ? Gm1[k] : Gc[k];      \
            int gp = __builtin_amdgcn_ds_bpermute(vs << 2, __float_as_int(gsel)); \
            float gv = ((unsigned)tsrc < (unsigned)NT) ? __int_as_float(gp) : 0.f; \
            float val = fmaf(s2[k], gv, sh2[k]);                                  \
            if (lane < V55) {                                                     \
                int oi = xbase + (dk * NT + (TOUT)) * V55 + lane;                 \
                out[oi] = fmaxf(val + x[oi], 0.f);                                \
            }                                                                     \
        }                                                                         \
    }

#define SUBITER(S, Gc, Gm1, Gm2)                                                  \
    {                                                                             \
        const int i  = 3 * m + (S);                                               \
        const int tc = t0 - 1 + i;                                                \
        const int ts = t0 + i;                                                    \
        __syncthreads();                                                          \
        float xv[8];                                                              \
        const bool dost = (ts < NT) && sact;                                      \
        STAGE_LOAD(ts, xv, dost);                                                 \
        const bool doc = ((unsigned)tc < (unsigned)NT);                           \
        COMPUTE(i & 1, Gc, doc);                                                  \
        STAGE_WRITE((i + 1) & 1, xv, dost);                                       \
        if (i >= 2) {                                                             \
            const int tout = t0 + i - 2;                                          \
            if (p3 == 0)      EMITP(0, Gc, Gm1, Gm2, tout)                        \
            else if (p3 == 1) EMITP(1, Gc, Gm1, Gm2, tout)                        \
            else              EMITP(2, Gc, Gm1, Gm2, tout)                        \
        }                                                                         \
    }

__global__ __launch_bounds__(512, 4)
void shiftgcn_fused2(const float* __restrict__ x, const float* __restrict__ Wm,
                     const float* __restrict__ bvec, const float* __restrict__ fm,
                     const float* __restrict__ bn1g, const float* __restrict__ bn1b,
                     const float* __restrict__ bn1m, const float* __restrict__ bn1v,
                     const float* __restrict__ bn2g, const float* __restrict__ bn2b,
                     const float* __restrict__ bn2m, const float* __restrict__ bn2v,
                     float* __restrict__ out)
{
    __shared__ __align__(16) float AT[2 * ATOFF];   // 32 KB, double-buffered

    const int tid  = threadIdx.x;
    const int lane = tid & 63;
    const int wv   = tid >> 6;                                  // 8 waves
    const int d0   = __builtin_amdgcn_readfirstlane(wv << 3);   // wave's d-slice base (SGPR)

    const int n  = blockIdx.x >> 3;
    const int t0 = (blockIdx.x & 7) << 4;
    const int xbase = n * (64 * NT * V55);

    // staging role: thread -> (c8, vb)
    const int c8 = tid & 7;
    const int vb = tid >> 3;               // 0..63, active when < 55
    const bool sact = vb < V55;
    int v0 = vb - c8; if (v0 < 0) v0 += V55; if (v0 >= V55) v0 -= V55;

    float msr[8];                          // mask factors (constant over t)
    if (sact) {
        int v = v0;
        #pragma unroll
        for (int j = 0; j < 8; ++j) {
            int c = (j << 3) + c8;
            msr[j] = tanhf(fm[v * 64 + c]) + 1.0f;
            v -= 8; if (v < 0) v += V55;
        }
    } else {
        #pragma unroll
        for (int j = 0; j < 8; ++j) msr[j] = 0.f;
    }

    // BN1 folded (per-lane: depends on v=lane and d); +b folded in
    const int vc = lane < V55 ? lane : V55 - 1;
    float s1[8], sh1[8];
    #pragma unroll
    for (int k = 0; k < 8; ++k) {
        int j = vc * 64 + d0 + k;
        float sc = bn1g[j] * rsqrtf(bn1v[j] + EPSF);
        s1[k]  = sc;
        sh1[k] = bn1b[j] - bn1m[j] * sc + sc * bvec[d0 + k];
    }
    // BN2 folded (wave-uniform per d) -> force into SGPRs
    float s2[8], sh2[8];
    #pragma unroll
    for (int k = 0; k < 8; ++k) {
        int dd = d0 + k;
        float sc = bn2g[dd] * rsqrtf(bn2v[dd] + EPSF);
        float sh = bn2b[dd] - bn2m[dd] * sc;
        s2[k]  = __int_as_float(__builtin_amdgcn_readfirstlane(__float_as_int(sc)));
        sh2[k] = __int_as_float(__builtin_amdgcn_readfirstlane(__float_as_int(sh)));
    }

    // g register ring: 3 generations of the wave's 8-d slice
    float gA[8], gB[8], gC[8];
    #pragma unroll
    for (int k = 0; k < 8; ++k) { gA[k] = 0.f; gB[k] = 0.f; gC[k] = 0.f; }

    const int p3 = d0 % 3;

    // prologue: stage t0-1 into buf 0
    {
        float xv[8];
        const bool dost = (t0 >= 1) && sact;
        STAGE_LOAD(t0 - 1, xv, dost);
        STAGE_WRITE(0, xv, dost);
    }

    for (int m = 0; m < 6; ++m) {
        SUBITER(0, gA, gC, gB)
        SUBITER(1, gB, gA, gC)
        SUBITER(2, gC, gB, gA)
    }
}

extern "C" void kernel_launch(void* const* d_in, const int* in_sizes, int n_in,
                              void* d_out, int out_size, void* d_ws, size_t ws_size,
                              hipStream_t stream) {
    const float* x    = (const float*)d_in[0];
    const float* Wm   = (const float*)d_in[1];
    const float* bvec = (const float*)d_in[2];
    const float* fm   = (const float*)d_in[3];
    const float* bn1g = (const float*)d_in[4];
    const float* bn1b = (const float*)d_in[5];
    const float* bn1m = (const float*)d_in[6];
    const float* bn1v = (const float*)d_in[7];
    const float* bn2g = (const float*)d_in[8];
    const float* bn2b = (const float*)d_in[9];
    const float* bn2m = (const float*)d_in[10];
    const float* bn2v = (const float*)d_in[11];
    float* out = (float*)d_out;

    shiftgcn_fused2<<<dim3(64 * 8), dim3(512), 0, stream>>>(
        x, Wm, bvec, fm, bn1g, bn1b, bn1m, bn1v, bn2g, bn2b, bn2m, bn2v, out);
}